// Round 4
// baseline (3019.598 us; speedup 1.0000x reference)
//
#include <hip/hip_runtime.h>

typedef __attribute__((ext_vector_type(8))) short short8;
typedef __attribute__((ext_vector_type(4))) float f32x4;
typedef __attribute__((ext_vector_type(4))) int i32x4;
typedef unsigned long long u64;

__device__ __forceinline__ unsigned short f2bf(float f) {
  unsigned u = __builtin_bit_cast(unsigned, f);
  u += 0x7fffu + ((u >> 16) & 1u);           // round-to-nearest-even
  return (unsigned short)(u >> 16);
}

__device__ __forceinline__ float fast_tanh(float x) {
  float e = __expf(2.0f * x);
  return 1.0f - __fdividef(2.0f, e + 1.0f);
}

// ---------------------------------------------------------------------------
// Generic C = A(fp32)[M,K] @ B(fp32)[K,N] + bias, via bf16 MFMA 16x16x32.
// (unchanged)
// ---------------------------------------------------------------------------
__global__ __launch_bounds__(256) void gemm_bias(
    const float* __restrict__ A, const float* __restrict__ B,
    const float* __restrict__ bias, float* __restrict__ C,
    int M, int N, int K)
{
  __shared__ short a_lds[128 * 32];
  __shared__ short b_lds[32 * 128];
  const int tid = threadIdx.x;
  const int lane = tid & 63;
  const int w = tid >> 6;
  const int wm = w >> 1, wn = w & 1;
  const long m0 = (long)blockIdx.x * 128;
  const int n0 = blockIdx.y * 128;

  f32x4 acc[4][4];
#pragma unroll
  for (int i = 0; i < 4; ++i)
#pragma unroll
    for (int j = 0; j < 4; ++j) acc[i][j] = (f32x4){0.f, 0.f, 0.f, 0.f};

  for (int k0 = 0; k0 < K; k0 += 32) {
#pragma unroll
    for (int it = 0; it < 2; ++it) {
      int tsk = tid + (it << 8);
      int r = tsk >> 2;
      int kg = tsk & 3;
      const float* src = A + (m0 + r) * (long)K + (k0 + kg * 8);
      float4 f0 = *(const float4*)src;
      float4 f1 = *(const float4*)(src + 4);
      short8 v;
      v[0] = f2bf(f0.x); v[1] = f2bf(f0.y); v[2] = f2bf(f0.z); v[3] = f2bf(f0.w);
      v[4] = f2bf(f1.x); v[5] = f2bf(f1.y); v[6] = f2bf(f1.z); v[7] = f2bf(f1.w);
      *(short8*)&a_lds[(((r >> 4) * 64) + kg * 16 + (r & 15)) * 8] = v;
    }
#pragma unroll
    for (int rep = 0; rep < 2; ++rep) {
      int nl = tid & 127;
      int kg = (tid >> 7) + rep * 2;
      const float* src = B + (long)(k0 + kg * 8) * N + (n0 + nl);
      short8 v;
#pragma unroll
      for (int r2 = 0; r2 < 8; ++r2) v[r2] = f2bf(src[(long)r2 * N]);
      *(short8*)&b_lds[(((nl >> 4) * 64) + kg * 16 + (nl & 15)) * 8] = v;
    }
    __syncthreads();
    short8 af[4], bfr[4];
#pragma unroll
    for (int mt = 0; mt < 4; ++mt)
      af[mt] = *(const short8*)&a_lds[((wm * 4 + mt) * 64 + lane) * 8];
#pragma unroll
    for (int nt = 0; nt < 4; ++nt)
      bfr[nt] = *(const short8*)&b_lds[((wn * 4 + nt) * 64 + lane) * 8];
#pragma unroll
    for (int mt = 0; mt < 4; ++mt)
#pragma unroll
      for (int nt = 0; nt < 4; ++nt)
        acc[mt][nt] = __builtin_amdgcn_mfma_f32_16x16x32_bf16(
            af[mt], bfr[nt], acc[mt][nt], 0, 0, 0);
    __syncthreads();
  }
#pragma unroll
  for (int nt = 0; nt < 4; ++nt) {
    int col = n0 + wn * 64 + nt * 16 + (lane & 15);
    float bv = bias[col];
#pragma unroll
    for (int mt = 0; mt < 4; ++mt) {
      long row = m0 + wm * 64 + mt * 16 + ((lane >> 4) * 4);
#pragma unroll
      for (int r = 0; r < 4; ++r)
        C[(row + r) * (long)N + col] = acc[mt][nt][r] + bv;
    }
  }
}

// ===========================================================================
// PATH A (needs >=512 KB workspace): flag-free tagged-packet scan.
// Packet = u64 { bf16 d0, bf16 d1, u32 tag } — 8B single-copy atomic, so a
// packet's tag validates its own data: no producer drain, no flag line.
// Producer of h_t stores tag=t+1; consumer at step t expects tag==t.
// hbuf: [2 slots][4 rings][32 chunks][16 rows][16 packets] = 512 KB.
// Consumer: sentinel-poll chunk heads -> pipelined 64x dwordx4 burst with
// counted vmcnt -> XOR tag check -> (rare) retry. WAR safe by dataflow:
// a peer reaches step t+1 only after consuming our h_t, which we publish
// only after our slot reads drained (vmcnt(0) at pipeline tail).
// Tags in the read slot are thus only {t-2, t}: exact-match check is sound
// and retries terminate.
// ===========================================================================

#define RNN_LOAD(P) \
    asm volatile("global_load_dwordx4 %0, %1, off sc0 sc1" \
        : "=v"(braw[(P) & 7][0]) : "v"(hrd + (size_t)(P) * 2048) : "memory"); \
    asm volatile("global_load_dwordx4 %0, %1, off sc0 sc1" \
        : "=v"(braw[(P) & 7][1]) : "v"(hrd + (size_t)(P) * 2048 + 16) : "memory");

#define RNN_STEP(P, WL) do { \
    asm volatile("s_waitcnt " WL ::: "memory"); \
    __builtin_amdgcn_sched_barrier(0); \
    i32x4 p0 = braw[(P) & 7][0]; \
    i32x4 p1 = braw[(P) & 7][1]; \
    diff |= (unsigned)(p0.y ^ (int)exp_tag) | (unsigned)(p0.w ^ (int)exp_tag) \
          | (unsigned)(p1.y ^ (int)exp_tag) | (unsigned)(p1.w ^ (int)exp_tag); \
    i32x4 bi; bi.x = p0.x; bi.y = p0.z; bi.z = p1.x; bi.w = p1.z; \
    short8 bfrag = __builtin_bit_cast(short8, bi); \
    short8 a0 = *(const short8*)&wlds[(((P) * 2 + 0) * 64 + lane) * 8]; \
    short8 a1 = *(const short8*)&wlds[(((P) * 2 + 1) * 64 + lane) * 8]; \
    acc0 = __builtin_amdgcn_mfma_f32_16x16x32_bf16(a0, bfrag, acc0, 0, 0, 0); \
    acc1 = __builtin_amdgcn_mfma_f32_16x16x32_bf16(a1, bfrag, acc1, 0, 0, 0); \
    if ((P) + 8 < 32) { RNN_LOAD((P) + 8) } \
  } while (0)

__global__ __launch_bounds__(64, 1) void rnn_scan_tagged(
    const float* __restrict__ Whh, float* __restrict__ xs,
    char* __restrict__ hbuf)
{
  __shared__ short wlds[32 * 2 * 64 * 8];  // 64 KB: W^T A-frags
  const int H = 1024;
  const int lane = threadIdx.x;
  const int wg = blockIdx.x;               // 0..127
  const int rg = wg >> 5;                  // ring (batch rows rg*16..+16)
  const int cg = wg & 31;                  // col group (h cols cg*32..+32)
  const int n0 = cg * 32;
  const int r0 = rg * 16;

  // stage W_hh[:, n0:n0+32] as A-frags of W^T
  for (int p = 0; p < 32; ++p) {
#pragma unroll
    for (int mt = 0; mt < 2; ++mt) {
      const float* src = Whh + (long)(p * 32 + (lane >> 4) * 8) * H
                       + (n0 + mt * 16 + (lane & 15));
      short8 v;
#pragma unroll
      for (int j = 0; j < 8; ++j) v[j] = f2bf(src[(long)j * H]);
      *(short8*)&wlds[(((p * 2 + mt) * 64) + lane) * 8] = v;
    }
  }
  __syncthreads();

  const int m = lane & 15;                 // batch row within chunk
  const int kq = lane >> 4;                // B-frag k sub-group (0..3)
  const int q4 = kq * 4;                   // C-frag col base
  const int q2 = kq * 2;                   // packet index base for publish

  i32x4 braw[8][2];                        // depth-8 chunk window

  for (int t = 0; t < 512; ++t) {
    const int slot_r = (t & 1) ^ 1;
    const int slot_w = t & 1;
    char* ring_r = hbuf + (size_t)slot_r * 262144 + (size_t)rg * 65536;
    char* ring_w = hbuf + (size_t)slot_w * 262144 + (size_t)rg * 65536;
    const char* hrd = ring_r + m * 128 + kq * 32;

    float* xrow = xs + (long)t * 64 * H;
    float* xbase = xrow + (long)(r0 + m) * H + n0 + q4;
    f32x4 xp0 = *(const f32x4*)xbase;
    f32x4 xp1 = *(const f32x4*)(xbase + 16);

    // sentinel poll: chunk-head packets of my ring
    {
      const u64* sp = (const u64*)(ring_r + (size_t)(lane & 31) * 2048);
      const bool need = lane < 32;
      while (true) {
        bool ok = true;
        if (need) {
          u64 v = __hip_atomic_load(sp, __ATOMIC_RELAXED, __HIP_MEMORY_SCOPE_AGENT);
          ok = ((unsigned)(v >> 32) >= (unsigned)t);
        }
        if (__all(ok)) break;
      }
    }
    asm volatile("s_waitcnt vmcnt(0)" ::: "memory");   // clean vmcnt baseline
    __builtin_amdgcn_sched_barrier(0);

    const unsigned exp_tag = (unsigned)t;
    f32x4 acc0, acc1;
    unsigned diff;
  retry:
    acc0 = (f32x4){0.f, 0.f, 0.f, 0.f};
    acc1 = (f32x4){0.f, 0.f, 0.f, 0.f};
    diff = 0u;
    RNN_LOAD(0) RNN_LOAD(1) RNN_LOAD(2) RNN_LOAD(3)
    RNN_LOAD(4) RNN_LOAD(5) RNN_LOAD(6) RNN_LOAD(7)
    RNN_STEP(0,  "vmcnt(14)"); RNN_STEP(1,  "vmcnt(14)"); RNN_STEP(2,  "vmcnt(14)");
    RNN_STEP(3,  "vmcnt(14)"); RNN_STEP(4,  "vmcnt(14)"); RNN_STEP(5,  "vmcnt(14)");
    RNN_STEP(6,  "vmcnt(14)"); RNN_STEP(7,  "vmcnt(14)"); RNN_STEP(8,  "vmcnt(14)");
    RNN_STEP(9,  "vmcnt(14)"); RNN_STEP(10, "vmcnt(14)"); RNN_STEP(11, "vmcnt(14)");
    RNN_STEP(12, "vmcnt(14)"); RNN_STEP(13, "vmcnt(14)"); RNN_STEP(14, "vmcnt(14)");
    RNN_STEP(15, "vmcnt(14)"); RNN_STEP(16, "vmcnt(14)"); RNN_STEP(17, "vmcnt(14)");
    RNN_STEP(18, "vmcnt(14)"); RNN_STEP(19, "vmcnt(14)"); RNN_STEP(20, "vmcnt(14)");
    RNN_STEP(21, "vmcnt(14)"); RNN_STEP(22, "vmcnt(14)"); RNN_STEP(23, "vmcnt(14)");
    RNN_STEP(24, "vmcnt(14)"); RNN_STEP(25, "vmcnt(12)"); RNN_STEP(26, "vmcnt(10)");
    RNN_STEP(27, "vmcnt(8)");  RNN_STEP(28, "vmcnt(6)");  RNN_STEP(29, "vmcnt(4)");
    RNN_STEP(30, "vmcnt(2)");  RNN_STEP(31, "vmcnt(0)");
    if (__any((int)(diff != 0u))) goto retry;   // rare packet-landing race

    float h0[4], h1[4];
    unsigned short b0[4], b1[4];
#pragma unroll
    for (int r = 0; r < 4; ++r) {
      h0[r] = fast_tanh(acc0[r] + xp0[r]);
      h1[r] = fast_tanh(acc1[r] + xp1[r]);
      b0[r] = f2bf(h0[r]);
      b1[r] = f2bf(h1[r]);
    }
    const u64 tw = ((u64)(unsigned)(t + 1)) << 32;
    char* hw = ring_w + (size_t)cg * 2048 + m * 128;
    __hip_atomic_store((u64*)(hw + (q2 + 0) * 8),
        (u64)((unsigned)b0[0] | ((unsigned)b0[1] << 16)) | tw,
        __ATOMIC_RELAXED, __HIP_MEMORY_SCOPE_AGENT);
    __hip_atomic_store((u64*)(hw + (q2 + 1) * 8),
        (u64)((unsigned)b0[2] | ((unsigned)b0[3] << 16)) | tw,
        __ATOMIC_RELAXED, __HIP_MEMORY_SCOPE_AGENT);
    __hip_atomic_store((u64*)(hw + (q2 + 8) * 8),
        (u64)((unsigned)b1[0] | ((unsigned)b1[1] << 16)) | tw,
        __ATOMIC_RELAXED, __HIP_MEMORY_SCOPE_AGENT);
    __hip_atomic_store((u64*)(hw + (q2 + 9) * 8),
        (u64)((unsigned)b1[2] | ((unsigned)b1[3] << 16)) | tw,
        __ATOMIC_RELAXED, __HIP_MEMORY_SCOPE_AGENT);

    *(f32x4*)xbase = (f32x4){h0[0], h0[1], h0[2], h0[3]};
    *(f32x4*)(xbase + 16) = (f32x4){h1[0], h1[1], h1[2], h1[3]};
  }
}

// ===========================================================================
// PATH B (fallback, 264 KB workspace): round-2 flag-based scan, verbatim —
// the kernel that passed at 2383 us total. Used when ws_size < Path A's need.
// ===========================================================================
__global__ __launch_bounds__(64, 1) void rnn_scan_flag(
    const float* __restrict__ Whh, float* __restrict__ xs,
    unsigned short* __restrict__ hbuf, int* __restrict__ flags)
{
  __shared__ short wlds[32 * 2 * 64 * 8];
  const int H = 1024;
  const int lane = threadIdx.x;
  const int wg = blockIdx.x;
  const int rg = wg >> 5;
  const int cg = wg & 31;
  const int n0 = cg * 32;
  const int r0 = rg * 16;

  for (int p = 0; p < 32; ++p) {
#pragma unroll
    for (int mt = 0; mt < 2; ++mt) {
      const float* src = Whh + (long)(p * 32 + (lane >> 4) * 8) * H
                       + (n0 + mt * 16 + (lane & 15));
      short8 v;
#pragma unroll
      for (int j = 0; j < 8; ++j) v[j] = f2bf(src[(long)j * H]);
      *(short8*)&wlds[(((p * 2 + mt) * 64) + lane) * 8] = v;
    }
  }
  __syncthreads();

  const int m = lane & 15;
  const int q4 = (lane >> 4) * 4;
  const int chunk_rd = m * 32 + (lane >> 4) * 8;
  const int myflag = wg * 4;
  union Pack { unsigned short us[4]; u64 q; };

  for (int t = 0; t < 512; ++t) {
    const int slot_r = (t & 1) ^ 1;
    const int slot_w = t & 1;
    float* xrow = xs + (long)t * 64 * H;
    float* xbase = xrow + (long)(r0 + m) * H + n0 + q4;

    f32x4 xp0 = *(const f32x4*)xbase;
    f32x4 xp1 = *(const f32x4*)(xbase + 16);

    if (lane < 32) {
      const int* fp = flags + (rg * 32 + lane) * 4;
      while (__hip_atomic_load(fp, __ATOMIC_RELAXED, __HIP_MEMORY_SCOPE_AGENT) < t) {}
    }

    const unsigned short* hrd =
        hbuf + (size_t)slot_r * 65536 + (size_t)rg * 16384 + chunk_rd;
    i32x4 hraw[32];
#pragma unroll
    for (int p = 0; p < 32; ++p) {
      asm volatile("global_load_dwordx4 %0, %1, off sc0 sc1"
                   : "=v"(hraw[p]) : "v"(hrd + (size_t)p * 512) : "memory");
    }
    asm volatile("s_waitcnt vmcnt(0)" ::: "memory");
    __builtin_amdgcn_sched_barrier(0);

    f32x4 acc0 = {0.f, 0.f, 0.f, 0.f}, acc1 = {0.f, 0.f, 0.f, 0.f};
#pragma unroll
    for (int p = 0; p < 32; ++p) {
      short8 a0 = *(const short8*)&wlds[((p * 2 + 0) * 64 + lane) * 8];
      short8 a1 = *(const short8*)&wlds[((p * 2 + 1) * 64 + lane) * 8];
      short8 hb = __builtin_bit_cast(short8, hraw[p]);
      acc0 = __builtin_amdgcn_mfma_f32_16x16x32_bf16(a0, hb, acc0, 0, 0, 0);
      acc1 = __builtin_amdgcn_mfma_f32_16x16x32_bf16(a1, hb, acc1, 0, 0, 0);
    }

    float h0[4], h1[4];
    Pack pv0, pv1;
#pragma unroll
    for (int r = 0; r < 4; ++r) {
      h0[r] = fast_tanh(acc0[r] + xp0[r]);
      h1[r] = fast_tanh(acc1[r] + xp1[r]);
      pv0.us[r] = f2bf(h0[r]);
      pv1.us[r] = f2bf(h1[r]);
    }
    unsigned short* hwr = hbuf + (size_t)slot_w * 65536 + (size_t)wg * 512;
    __hip_atomic_store((u64*)(hwr + m * 32 + q4), pv0.q,
                       __ATOMIC_RELAXED, __HIP_MEMORY_SCOPE_AGENT);
    __hip_atomic_store((u64*)(hwr + m * 32 + 16 + q4), pv1.q,
                       __ATOMIC_RELAXED, __HIP_MEMORY_SCOPE_AGENT);
    asm volatile("s_waitcnt vmcnt(0)" ::: "memory");
    if (lane == 0)
      __hip_atomic_store(flags + myflag, t + 1,
                         __ATOMIC_RELAXED, __HIP_MEMORY_SCOPE_AGENT);

    *(f32x4*)xbase = (f32x4){h0[0], h0[1], h0[2], h0[3]};
    *(f32x4*)(xbase + 16) = (f32x4){h1[0], h1[1], h1[2], h1[3]};
  }
}

extern "C" void kernel_launch(void* const* d_in, const int* in_sizes, int n_in,
                              void* d_out, int out_size, void* d_ws, size_t ws_size,
                              hipStream_t stream)
{
  const float* X   = (const float*)d_in[0];  // [512,64,512]
  const float* Wxh = (const float*)d_in[1];  // [512,1024]
  const float* Whh = (const float*)d_in[2];  // [1024,1024]
  const float* bh  = (const float*)d_in[3];  // [1024]
  const float* Whq = (const float*)d_in[4];  // [1024,512]
  const float* bq  = (const float*)d_in[5];  // [512]

  float* outputs = (float*)d_out;                       // [512,64,512]
  float* states  = outputs + (long)512 * 64 * 512;      // [512,64,1024]

  // phase 1: Xproj = X @ W_xh + b_h  -> states region (consumed in-place)
  dim3 g1(32768 / 128, 1024 / 128);
  gemm_bias<<<g1, 256, 0, stream>>>(X, Wxh, bh, states, 32768, 1024, 512);

  // phase 2: sequential scan — pick protocol by available workspace.
  if (ws_size >= (size_t)524288) {
    // tagged-packet path: 512 KB hbuf, no flags
    hipMemsetAsync(d_ws, 0, (size_t)524288, stream);
    rnn_scan_tagged<<<128, 64, 0, stream>>>(Whh, states, (char*)d_ws);
  } else {
    // flag path (proven): 256 KB hbuf + 2 KB padded flags
    unsigned short* hbuf = (unsigned short*)d_ws;
    int* flags = (int*)((char*)d_ws + (size_t)2 * 64 * 1024 * 2);
    hipMemsetAsync(d_ws, 0, (size_t)2 * 64 * 1024 * 2 + 2048, stream);
    rnn_scan_flag<<<128, 64, 0, stream>>>(Whh, states, hbuf, flags);
  }

  // phase 3: outputs = states @ W_hq + b_q
  dim3 g3(32768 / 128, 512 / 128);
  gemm_bias<<<g3, 256, 0, stream>>>(states, Whq, bq, outputs, 32768, 512, 1024);
}

// Round 5
// 2335.588 us; speedup vs baseline: 1.2929x; 1.2929x over previous
//
#include <hip/hip_runtime.h>

typedef __attribute__((ext_vector_type(8))) short short8;
typedef __attribute__((ext_vector_type(4))) float f32x4;
typedef __attribute__((ext_vector_type(4))) int i32x4;
typedef unsigned long long u64;

__device__ __forceinline__ unsigned short f2bf(float f) {
  unsigned u = __builtin_bit_cast(unsigned, f);
  u += 0x7fffu + ((u >> 16) & 1u);           // round-to-nearest-even
  return (unsigned short)(u >> 16);
}

__device__ __forceinline__ float fast_tanh(float x) {
  float e = __expf(2.0f * x);
  return 1.0f - __fdividef(2.0f, e + 1.0f);
}

// ---------------------------------------------------------------------------
// Weight pre-conversion: fp32 W[K,N] -> bf16 blob in b_lds FRAGMENT order.
// blob tile (tk,tn) base = (tk*(N/128)+tn)*4096 shorts; within a tile:
//   short index ((nt*64 + kg*16 + m)*8 + r) = W[tk*32 + kg*8 + r][tn*128 + nt*16 + m]
// This is exactly the layout gemm staging used to build per-kstep, so the
// GEMM's B staging becomes a pure coalesced copy.
// ---------------------------------------------------------------------------
__global__ __launch_bounds__(256) void conv_wblob(
    const float* __restrict__ W, unsigned short* __restrict__ blob,
    int K, int N)
{
  int id = blockIdx.x * 256 + threadIdx.x;   // total = (K/32)*(N/128)*128
  int m  = id & 15;
  int nt = (id >> 4) & 7;
  int tn = (id >> 7) % (N / 128);
  int tk = (id >> 7) / (N / 128);
  if (tk >= K / 32) return;
  int col = tn * 128 + nt * 16 + m;
  unsigned short* dst = blob + (size_t)(tk * (N / 128) + tn) * 4096 + (size_t)nt * 512;
  const float* src = W + (size_t)(tk * 32) * N + col;
#pragma unroll
  for (int kg = 0; kg < 4; ++kg) {
    short8 v;
#pragma unroll
    for (int r = 0; r < 8; ++r)
      v[r] = (short)f2bf(src[(size_t)(kg * 8 + r) * N]);
    *(short8*)&dst[(kg * 16 + m) * 8] = v;
  }
}

// ---------------------------------------------------------------------------
// GEMM with pre-swizzled bf16 B blob: C = A(fp32)[M,K] @ B[K,N] + bias.
// 128x128 tile, BK=32, 256 threads (4 waves 2x2, each 64x64 = 4x4 frags).
// B staging = 2 coalesced short8 copies/thread (no cvt, no strided loads).
// ---------------------------------------------------------------------------
__global__ __launch_bounds__(256) void gemm_bias_blob(
    const float* __restrict__ A, const unsigned short* __restrict__ Bblob,
    const float* __restrict__ bias, float* __restrict__ C,
    int M, int N, int K)
{
  __shared__ short a_lds[128 * 32];
  __shared__ short b_lds[32 * 128];
  const int tid = threadIdx.x;
  const int lane = tid & 63;
  const int w = tid >> 6;
  const int wm = w >> 1, wn = w & 1;
  const long m0 = (long)blockIdx.x * 128;
  const int tiles_n = N >> 7;

  f32x4 acc[4][4];
#pragma unroll
  for (int i = 0; i < 4; ++i)
#pragma unroll
    for (int j = 0; j < 4; ++j) acc[i][j] = (f32x4){0.f, 0.f, 0.f, 0.f};

  for (int k0 = 0; k0 < K; k0 += 32) {
#pragma unroll
    for (int it = 0; it < 2; ++it) {
      int tsk = tid + (it << 8);
      int r = tsk >> 2;
      int kg = tsk & 3;
      const float* src = A + (m0 + r) * (long)K + (k0 + kg * 8);
      float4 f0 = *(const float4*)src;
      float4 f1 = *(const float4*)(src + 4);
      short8 v;
      v[0] = f2bf(f0.x); v[1] = f2bf(f0.y); v[2] = f2bf(f0.z); v[3] = f2bf(f0.w);
      v[4] = f2bf(f1.x); v[5] = f2bf(f1.y); v[6] = f2bf(f1.z); v[7] = f2bf(f1.w);
      *(short8*)&a_lds[(((r >> 4) * 64) + kg * 16 + (r & 15)) * 8] = v;
    }
    {
      const unsigned short* bsrc =
          Bblob + (size_t)((k0 >> 5) * tiles_n + blockIdx.y) * 4096;
      *(short8*)&b_lds[tid * 8]         = *(const short8*)&bsrc[tid * 8];
      *(short8*)&b_lds[(tid + 256) * 8] = *(const short8*)&bsrc[(tid + 256) * 8];
    }
    __syncthreads();
    short8 af[4], bfr[4];
#pragma unroll
    for (int mt = 0; mt < 4; ++mt)
      af[mt] = *(const short8*)&a_lds[((wm * 4 + mt) * 64 + lane) * 8];
#pragma unroll
    for (int nt = 0; nt < 4; ++nt)
      bfr[nt] = *(const short8*)&b_lds[((wn * 4 + nt) * 64 + lane) * 8];
#pragma unroll
    for (int mt = 0; mt < 4; ++mt)
#pragma unroll
      for (int nt = 0; nt < 4; ++nt)
        acc[mt][nt] = __builtin_amdgcn_mfma_f32_16x16x32_bf16(
            af[mt], bfr[nt], acc[mt][nt], 0, 0, 0);
    __syncthreads();
  }
#pragma unroll
  for (int nt = 0; nt < 4; ++nt) {
    int col = blockIdx.y * 128 + wn * 64 + nt * 16 + (lane & 15);
    float bv = bias[col];
#pragma unroll
    for (int mt = 0; mt < 4; ++mt) {
      long row = m0 + wm * 64 + mt * 16 + ((lane >> 4) * 4);
#pragma unroll
      for (int r = 0; r < 4; ++r)
        C[(row + r) * (long)N + col] = acc[mt][nt][r] + bv;
    }
  }
}

// ---------------------------------------------------------------------------
// Fallback GEMM (fp32 B), verbatim from the round-2 kernel.
// ---------------------------------------------------------------------------
__global__ __launch_bounds__(256) void gemm_bias(
    const float* __restrict__ A, const float* __restrict__ B,
    const float* __restrict__ bias, float* __restrict__ C,
    int M, int N, int K)
{
  __shared__ short a_lds[128 * 32];
  __shared__ short b_lds[32 * 128];
  const int tid = threadIdx.x;
  const int lane = tid & 63;
  const int w = tid >> 6;
  const int wm = w >> 1, wn = w & 1;
  const long m0 = (long)blockIdx.x * 128;
  const int n0 = blockIdx.y * 128;

  f32x4 acc[4][4];
#pragma unroll
  for (int i = 0; i < 4; ++i)
#pragma unroll
    for (int j = 0; j < 4; ++j) acc[i][j] = (f32x4){0.f, 0.f, 0.f, 0.f};

  for (int k0 = 0; k0 < K; k0 += 32) {
#pragma unroll
    for (int it = 0; it < 2; ++it) {
      int tsk = tid + (it << 8);
      int r = tsk >> 2;
      int kg = tsk & 3;
      const float* src = A + (m0 + r) * (long)K + (k0 + kg * 8);
      float4 f0 = *(const float4*)src;
      float4 f1 = *(const float4*)(src + 4);
      short8 v;
      v[0] = f2bf(f0.x); v[1] = f2bf(f0.y); v[2] = f2bf(f0.z); v[3] = f2bf(f0.w);
      v[4] = f2bf(f1.x); v[5] = f2bf(f1.y); v[6] = f2bf(f1.z); v[7] = f2bf(f1.w);
      *(short8*)&a_lds[(((r >> 4) * 64) + kg * 16 + (r & 15)) * 8] = v;
    }
#pragma unroll
    for (int rep = 0; rep < 2; ++rep) {
      int nl = tid & 127;
      int kg = (tid >> 7) + rep * 2;
      const float* src = B + (long)(k0 + kg * 8) * N + (n0 + nl);
      short8 v;
#pragma unroll
      for (int r2 = 0; r2 < 8; ++r2) v[r2] = f2bf(src[(long)r2 * N]);
      *(short8*)&b_lds[(((nl >> 4) * 64) + kg * 16 + (nl & 15)) * 8] = v;
    }
    __syncthreads();
    short8 af[4], bfr[4];
#pragma unroll
    for (int mt = 0; mt < 4; ++mt)
      af[mt] = *(const short8*)&a_lds[((wm * 4 + mt) * 64 + lane) * 8];
#pragma unroll
    for (int nt = 0; nt < 4; ++nt)
      bfr[nt] = *(const short8*)&b_lds[((wn * 4 + nt) * 64 + lane) * 8];
#pragma unroll
    for (int mt = 0; mt < 4; ++mt)
#pragma unroll
      for (int nt = 0; nt < 4; ++nt)
        acc[mt][nt] = __builtin_amdgcn_mfma_f32_16x16x32_bf16(
            af[mt], bfr[nt], acc[mt][nt], 0, 0, 0);
    __syncthreads();
  }
#pragma unroll
  for (int nt = 0; nt < 4; ++nt) {
    int col = n0 + wn * 64 + nt * 16 + (lane & 15);
    float bv = bias[col];
#pragma unroll
    for (int mt = 0; mt < 4; ++mt) {
      long row = m0 + wm * 64 + mt * 16 + ((lane >> 4) * 4);
#pragma unroll
      for (int r = 0; r < 4; ++r)
        C[(row + r) * (long)N + col] = acc[mt][nt][r] + bv;
    }
  }
}

// ---------------------------------------------------------------------------
// Persistent RNN scan — round-2 flag protocol, verbatim (proven 2021 us).
// 128 wgs x 64 threads (1 wave), 4 independent rings of 32; wg = rg*32+cg
// owns batch rows rg*16..+16 and h-cols cg*32..+32. Transposed MFMA
// (W^T as A-op, h^T as B-op) -> C-frag = 4 consecutive h-cols -> direct
// packed publish. Burst coherent loads -> regs, one vmcnt(0), pure MFMA.
// hbuf [2 slots][4 rg][32 cg][16 rows][32 cols] bf16 = 256 KB; flags 16B pad.
// ---------------------------------------------------------------------------
__global__ __launch_bounds__(64, 1) void rnn_scan(
    const float* __restrict__ Whh, float* __restrict__ xs,
    unsigned short* __restrict__ hbuf, int* __restrict__ flags)
{
  __shared__ short wlds[32 * 2 * 64 * 8];  // 64 KB: W^T in MFMA A-frag order
  const int H = 1024;
  const int lane = threadIdx.x;
  const int wg = blockIdx.x;
  const int rg = wg >> 5;
  const int cg = wg & 31;
  const int n0 = cg * 32;
  const int r0 = rg * 16;

  // stage W_hh[:, n0:n0+32] as A-frags of W^T
  for (int p = 0; p < 32; ++p) {
#pragma unroll
    for (int mt = 0; mt < 2; ++mt) {
      const float* src = Whh + (long)(p * 32 + (lane >> 4) * 8) * H
                       + (n0 + mt * 16 + (lane & 15));
      short8 v;
#pragma unroll
      for (int j = 0; j < 8; ++j) v[j] = f2bf(src[(long)j * H]);
      *(short8*)&wlds[(((p * 2 + mt) * 64) + lane) * 8] = v;
    }
  }
  __syncthreads();

  const int m = lane & 15;                 // batch row within chunk
  const int q4 = (lane >> 4) * 4;          // C-frag col base
  const int chunk_rd = m * 32 + (lane >> 4) * 8;
  const int myflag = wg * 4;
  union Pack { unsigned short us[4]; u64 q; };

  for (int t = 0; t < 512; ++t) {
    const int slot_r = (t & 1) ^ 1;
    const int slot_w = t & 1;
    float* xrow = xs + (long)t * 64 * H;
    float* xbase = xrow + (long)(r0 + m) * H + n0 + q4;

    f32x4 xp0 = *(const f32x4*)xbase;
    f32x4 xp1 = *(const f32x4*)(xbase + 16);

    if (lane < 32) {
      const int* fp = flags + (rg * 32 + lane) * 4;
      while (__hip_atomic_load(fp, __ATOMIC_RELAXED, __HIP_MEMORY_SCOPE_AGENT) < t) {}
    }

    const unsigned short* hrd =
        hbuf + (size_t)slot_r * 65536 + (size_t)rg * 16384 + chunk_rd;
    i32x4 hraw[32];
#pragma unroll
    for (int p = 0; p < 32; ++p) {
      asm volatile("global_load_dwordx4 %0, %1, off sc0 sc1"
                   : "=v"(hraw[p]) : "v"(hrd + (size_t)p * 512) : "memory");
    }
    asm volatile("s_waitcnt vmcnt(0)" ::: "memory");
    __builtin_amdgcn_sched_barrier(0);

    f32x4 acc0 = {0.f, 0.f, 0.f, 0.f}, acc1 = {0.f, 0.f, 0.f, 0.f};
#pragma unroll
    for (int p = 0; p < 32; ++p) {
      short8 a0 = *(const short8*)&wlds[((p * 2 + 0) * 64 + lane) * 8];
      short8 a1 = *(const short8*)&wlds[((p * 2 + 1) * 64 + lane) * 8];
      short8 hb = __builtin_bit_cast(short8, hraw[p]);
      acc0 = __builtin_amdgcn_mfma_f32_16x16x32_bf16(a0, hb, acc0, 0, 0, 0);
      acc1 = __builtin_amdgcn_mfma_f32_16x16x32_bf16(a1, hb, acc1, 0, 0, 0);
    }

    float h0[4], h1[4];
    Pack pv0, pv1;
#pragma unroll
    for (int r = 0; r < 4; ++r) {
      h0[r] = fast_tanh(acc0[r] + xp0[r]);
      h1[r] = fast_tanh(acc1[r] + xp1[r]);
      pv0.us[r] = f2bf(h0[r]);
      pv1.us[r] = f2bf(h1[r]);
    }
    unsigned short* hwr = hbuf + (size_t)slot_w * 65536 + (size_t)wg * 512;
    __hip_atomic_store((u64*)(hwr + m * 32 + q4), pv0.q,
                       __ATOMIC_RELAXED, __HIP_MEMORY_SCOPE_AGENT);
    __hip_atomic_store((u64*)(hwr + m * 32 + 16 + q4), pv1.q,
                       __ATOMIC_RELAXED, __HIP_MEMORY_SCOPE_AGENT);
    asm volatile("s_waitcnt vmcnt(0)" ::: "memory");
    if (lane == 0)
      __hip_atomic_store(flags + myflag, t + 1,
                         __ATOMIC_RELAXED, __HIP_MEMORY_SCOPE_AGENT);

    *(f32x4*)xbase = (f32x4){h0[0], h0[1], h0[2], h0[3]};
    *(f32x4*)(xbase + 16) = (f32x4){h1[0], h1[1], h1[2], h1[3]};
  }
}

extern "C" void kernel_launch(void* const* d_in, const int* in_sizes, int n_in,
                              void* d_out, int out_size, void* d_ws, size_t ws_size,
                              hipStream_t stream)
{
  const float* X   = (const float*)d_in[0];  // [512,64,512]
  const float* Wxh = (const float*)d_in[1];  // [512,1024]
  const float* Whh = (const float*)d_in[2];  // [1024,1024]
  const float* bh  = (const float*)d_in[3];  // [1024]
  const float* Whq = (const float*)d_in[4];  // [1024,512]
  const float* bq  = (const float*)d_in[5];  // [512]

  float* outputs = (float*)d_out;                       // [512,64,512]
  float* states  = outputs + (long)512 * 64 * 512;      // [512,64,1024]

  // workspace layout:
  //   [0, 262144)            hbuf (2 slots x 4 rings x 32 KB bf16)
  //   [262144, 264192)       flags (128 x 16 B)
  //   [327680, +1 MB)        Wxh bf16 blob  (fast path only)
  //   [1376256, +1 MB)       Whq bf16 blob  (fast path only)
  unsigned short* hbuf = (unsigned short*)d_ws;
  int* flags = (int*)((char*)d_ws + 262144);
  unsigned short* bxh = (unsigned short*)((char*)d_ws + 327680);
  unsigned short* bhq = (unsigned short*)((char*)d_ws + 1376256);
  const bool fast = ws_size >= (size_t)2424832;

  hipMemsetAsync(d_ws, 0, (size_t)264192, stream);

  dim3 g1(32768 / 128, 1024 / 128);
  dim3 g3(32768 / 128, 512 / 128);

  if (fast) {
    // pre-swizzle weights to bf16 blobs (one-time, ~2 MB total)
    conv_wblob<<<64, 256, 0, stream>>>(Wxh, bxh, 512, 1024);
    conv_wblob<<<64, 256, 0, stream>>>(Whq, bhq, 1024, 512);
    gemm_bias_blob<<<g1, 256, 0, stream>>>(X, bxh, bh, states, 32768, 1024, 512);
    rnn_scan<<<128, 64, 0, stream>>>(Whh, states, hbuf, flags);
    gemm_bias_blob<<<g3, 256, 0, stream>>>(states, bhq, bq, outputs, 32768, 512, 1024);
  } else {
    gemm_bias<<<g1, 256, 0, stream>>>(X, Wxh, bh, states, 32768, 1024, 512);
    rnn_scan<<<128, 64, 0, stream>>>(Whh, states, hbuf, flags);
    gemm_bias<<<g3, 256, 0, stream>>>(states, Whq, bq, outputs, 32768, 512, 1024);
  }
}